// Round 7
// baseline (642.504 us; speedup 1.0000x reference)
//
#include <hip/hip_runtime.h>
#include <math.h>

#define TOK 8192   // B*S tokens
#define HD  512    // hidden
#define NE  8      // experts
#define DFF 2048   // ffn dim

// ---------- bf16 helpers ----------
typedef __attribute__((ext_vector_type(8))) short bf16x8;
typedef __attribute__((ext_vector_type(4))) float floatx4;

__device__ inline unsigned short f2bf(float f) {
    union { float f; unsigned u; } v; v.f = f;
    unsigned r = v.u + 0x7FFFu + ((v.u >> 16) & 1u);   // round-nearest-even
    return (unsigned short)(r >> 16);
}

__device__ inline float gelu_exact(float v) {
    return 0.5f * v * (1.f + erff(v * 0.70710678118654752f));
}

// ---------------- gating (fp32, exact) + fused x->bf16 conversion ----------------
__global__ __launch_bounds__(256) void gate_kernel(
    const float* __restrict__ x, const float* __restrict__ gW, const float* __restrict__ gb,
    int* __restrict__ seg_count, float* __restrict__ probs_sum,
    int* __restrict__ seg_token, float* __restrict__ seg_w,
    unsigned short* __restrict__ xb)
{
    __shared__ float sW[HD * NE];
    __shared__ float psum[NE];
    __shared__ int   lcount[NE];
    __shared__ int   lbase[NE];

    int tid = threadIdx.x;
    for (int i = tid; i < HD * NE; i += 256) sW[i] = gW[i];
    if (tid < NE) { psum[tid] = 0.f; lcount[tid] = 0; }
    __syncthreads();

    int t = blockIdx.x * 256 + tid;
    float logit[NE];
    #pragma unroll
    for (int e = 0; e < NE; e++) logit[e] = gb[e];

    const float4* xr4 = reinterpret_cast<const float4*>(x + (size_t)t * HD);
    ushort4* xbw = reinterpret_cast<ushort4*>(xb + (size_t)t * HD);
    for (int j4 = 0; j4 < HD / 4; j4++) {
        float4 xv = xr4[j4];
        int j = j4 * 4;
        ushort4 o; o.x = f2bf(xv.x); o.y = f2bf(xv.y); o.z = f2bf(xv.z); o.w = f2bf(xv.w);
        xbw[j4] = o;
        #pragma unroll
        for (int e = 0; e < NE; e++) {
            logit[e] += xv.x * sW[(j + 0) * NE + e] + xv.y * sW[(j + 1) * NE + e]
                      + xv.z * sW[(j + 2) * NE + e] + xv.w * sW[(j + 3) * NE + e];
        }
    }

    float mx = logit[0];
    #pragma unroll
    for (int e = 1; e < NE; e++) mx = fmaxf(mx, logit[e]);
    float pe[NE]; float s = 0.f;
    #pragma unroll
    for (int e = 0; e < NE; e++) { pe[e] = expf(logit[e] - mx); s += pe[e]; }
    float inv = 1.f / s;
    int l = tid & 63;
    #pragma unroll
    for (int e = 0; e < NE; e++) {          // wave-shuffle reduce, 1 LDS atomic per wave per e
        float v = pe[e] * inv;
        for (int off = 32; off; off >>= 1) v += __shfl_down(v, off);
        if (l == 0) atomicAdd(&psum[e], v);
    }

    // top-2, lowest-index tie break (matches jax.lax.top_k)
    int i0 = 0; float v0 = logit[0];
    #pragma unroll
    for (int e = 1; e < NE; e++) if (logit[e] > v0) { v0 = logit[e]; i0 = e; }
    int i1 = -1; float v1 = -3.4e38f;
    #pragma unroll
    for (int e = 0; e < NE; e++) if (e != i0 && logit[e] > v1) { v1 = logit[e]; i1 = e; }
    float e1 = expf(v1 - v0);
    float w0 = 1.f / (1.f + e1);
    float w1 = e1 / (1.f + e1);

    int r0 = atomicAdd(&lcount[i0], 1);
    int r1 = atomicAdd(&lcount[i1], 1);
    __syncthreads();
    if (tid < NE) lbase[tid] = atomicAdd(&seg_count[tid], lcount[tid]);
    __syncthreads();
    int p0 = lbase[i0] + r0;
    seg_token[i0 * TOK + p0] = t; seg_w[i0 * TOK + p0] = w0;
    int p1 = lbase[i1] + r1;
    seg_token[i1 * TOK + p1] = t; seg_w[i1 * TOK + p1] = w1;

    __syncthreads();
    if (tid < NE) atomicAdd(&probs_sum[tid], psum[tid]);
}

// ---------------- l_aux + counts ----------------
__global__ void finalize_kernel(const int* __restrict__ seg_count,
                                const float* __restrict__ probs_sum,
                                float* __restrict__ out_tail)
{
    int tid = threadIdx.x;
    __shared__ float p2[NE];
    if (tid < NE) {
        float p = probs_sum[tid] * (1.f / (float)TOK);
        p2[tid] = p * p;
        out_tail[1 + tid] = (float)seg_count[tid];
    }
    __syncthreads();
    if (tid == 0) {
        float ssum = 0.f;
        #pragma unroll
        for (int e = 0; e < NE; e++) ssum += p2[e];
        out_tail[0] = ssum * (float)NE;
    }
}

// ---------------- weight transpose (both W1 and W2 in one launch) ----------------
// z < NE : W1 [e][HD][DFF] -> W1t [e][DFF][HD]
// z >= NE: W2 [e][DFF][HD] -> W2t [e][HD][DFF]
__global__ __launch_bounds__(256) void transpose_both_kernel(
    const float* __restrict__ W1, const float* __restrict__ W2,
    unsigned short* __restrict__ W1t, unsigned short* __restrict__ W2t)
{
    __shared__ float tile[64][65];
    int z = blockIdx.z;
    const float* src; unsigned short* dst; int C, R, cb, rb;
    if (z < NE) {
        src = W1 + (size_t)z * HD * DFF; dst = W1t + (size_t)z * HD * DFF;
        R = HD; C = DFF; cb = blockIdx.x; rb = blockIdx.y;        // C/64=32, R/64=8
    } else {
        int e = z - NE;
        src = W2 + (size_t)e * DFF * HD; dst = W2t + (size_t)e * DFF * HD;
        R = DFF; C = HD; cb = blockIdx.y; rb = blockIdx.x;        // C/64=8, R/64=32
    }
    int c0 = cb * 64, r0 = rb * 64;
    int lc = threadIdx.x & 63, lrw = threadIdx.x >> 6;
    #pragma unroll
    for (int rr = lrw; rr < 64; rr += 4)
        tile[rr][lc] = src[(size_t)(r0 + rr) * C + c0 + lc];
    __syncthreads();
    #pragma unroll
    for (int cc = lrw; cc < 64; cc += 4)
        dst[(size_t)(c0 + cc) * R + r0 + lc] = f2bf(tile[lc][cc]);
}

// ---------------- prefix + gather (parallel): 128-padded per-expert row segments ----------------
#define RPAD 128
__global__ void prefix_gather_kernel(const int* __restrict__ seg_count,
                                     const int* __restrict__ seg_token,
                                     const float* __restrict__ seg_w,
                                     int* __restrict__ off_g,
                                     int* __restrict__ rtok, float* __restrict__ rwgt)
{
    __shared__ int off_s[NE + 1];
    if (threadIdx.x == 0) {
        int acc = 0;
        #pragma unroll
        for (int e = 0; e < NE; e++) {
            off_s[e] = acc;
            if (blockIdx.x == 0) off_g[e] = acc;
            acc += ((seg_count[e] + RPAD - 1) / RPAD) * RPAD;
        }
        off_s[NE] = acc;
        if (blockIdx.x == 0) off_g[NE] = acc;
    }
    __syncthreads();
    int total = off_s[NE];
    int i = blockIdx.x * 256 + threadIdx.x;
    if (i >= total) return;
    int e = 0;
    #pragma unroll
    for (int ee = 0; ee < NE; ee++) if (i >= off_s[ee + 1]) e = ee + 1;
    int li = i - off_s[e];
    int cnt = seg_count[e];
    if (li < cnt) { rtok[i] = seg_token[e * TOK + li]; rwgt[i] = seg_w[e * TOK + li]; }
    else          { rtok[i] = seg_token[e * TOK];      rwgt[i] = 0.f; }   // pad: dup row0, weight 0
}

// ---------------- split GEMM path (software-pipelined) ----------------
// 128x128 tiles, BK=64, 4 waves each 64x64. Double-buffered LDS + VGPR
// prefetch of tile k+1 before computing tile k -> ONE barrier per K-iter,
// global latency covered by the MFMA section.
#define TM  128
#define TN  128
#define BK  64
#define LDT 72          // padded LDS leading dim (ushorts)
#define TILE (TM * LDT) // one A or B tile in ushorts
#define BUFSZ (2 * TILE)

// GEMM1: hbuf[row, n] = gelu( xb[rtok[row], :] @ W1t[e][n, :] + b1[e][n] )
__global__ __launch_bounds__(256) void gemm1_kernel(
    const unsigned short* __restrict__ xb,
    const unsigned short* __restrict__ W1t,   // [E][DFF][HD] n-major
    const float* __restrict__ b1,
    const int* __restrict__ seg_count, const int* __restrict__ off_g,
    const int* __restrict__ rtok,
    unsigned short* __restrict__ hbuf)        // [rows][DFF]
{
    int bid = blockIdx.x;
    int e   = bid & 7;                         // low bits -> XCD affinity
    int r2  = bid >> 3;
    int nb  = r2 & (DFF / TN - 1);
    int mb  = r2 >> 4;
    int cnt = seg_count[e];
    if (mb * TM >= cnt) return;
    int hb = off_g[e] + mb * TM;

    __shared__ unsigned short smem[2 * BUFSZ];   // [buf][A|B] = 73728 B
    __shared__ int tok_s[TM];

    int tid = threadIdx.x;
    if (tid < TM) tok_s[tid] = rtok[hb + tid];
    __syncthreads();

    int w = tid >> 6, l = tid & 63;
    int lr = l & 15, lk = (l >> 4) * 8, crow = (l >> 4) * 4;
    int wm = (w & 1) * 64, wn = (w >> 1) * 64;

    const unsigned short* w1e = W1t + (size_t)e * DFF * HD + (size_t)(nb * TN) * HD;

    floatx4 acc[4][4];
    #pragma unroll
    for (int i = 0; i < 4; i++)
        #pragma unroll
        for (int j = 0; j < 4; j++) acc[i][j] = (floatx4){0.f, 0.f, 0.f, 0.f};

    int sr = tid >> 1, sh = (tid & 1) * 32;   // staging: 2 threads/row, 64 B each
    const uint4* ga = (const uint4*)(xb + (size_t)tok_s[sr] * HD + sh);   // row stride 64 uint4
    const uint4* gb4 = (const uint4*)(w1e + (size_t)sr * HD + sh);
    int sofs = sr * LDT + sh;                  // ushort offset in tile

    uint4 ra[4], rb[4];
    #pragma unroll
    for (int i = 0; i < 4; i++) { ra[i] = ga[i]; rb[i] = gb4[i]; }
    {   // store tile 0 -> buf 0
        uint4* da = (uint4*)&smem[sofs];
        uint4* db = (uint4*)&smem[TILE + sofs];
        #pragma unroll
        for (int i = 0; i < 4; i++) { da[i] = ra[i]; db[i] = rb[i]; }
    }
    __syncthreads();

    int buf = 0;
    for (int k0 = 0; k0 < HD; k0 += BK) {
        int nk = k0 + BK;
        if (nk < HD) {                         // prefetch next tile into regs
            int o = nk >> 3;
            #pragma unroll
            for (int i = 0; i < 4; i++) { ra[i] = ga[o + i]; rb[i] = gb4[o + i]; }
        }
        const unsigned short* A = smem + buf * BUFSZ;
        const unsigned short* B = A + TILE;
        #pragma unroll
        for (int ks = 0; ks < BK; ks += 32) {
            bf16x8 a[4], b[4];
            #pragma unroll
            for (int i = 0; i < 4; i++) a[i] = *(const bf16x8*)&A[(wm + 16 * i + lr) * LDT + ks + lk];
            #pragma unroll
            for (int j = 0; j < 4; j++) b[j] = *(const bf16x8*)&B[(wn + 16 * j + lr) * LDT + ks + lk];
            #pragma unroll
            for (int i = 0; i < 4; i++)
                #pragma unroll
                for (int j = 0; j < 4; j++)
                    acc[i][j] = __builtin_amdgcn_mfma_f32_16x16x32_bf16(a[i], b[j], acc[i][j], 0, 0, 0);
        }
        if (nk < HD) {
            buf ^= 1;
            uint4* da = (uint4*)&smem[buf * BUFSZ + sofs];
            uint4* db = (uint4*)&smem[buf * BUFSZ + TILE + sofs];
            #pragma unroll
            for (int i = 0; i < 4; i++) { da[i] = ra[i]; db[i] = rb[i]; }
            __syncthreads();
        }
    }
    __syncthreads();   // everyone done with LDS tiles before scratch reuse

    // epilogue: +b1, gelu, bf16 -> per-wave LDS scratch -> coalesced 16B stores
    unsigned short* scr = smem + w * 64 * LDT;
    #pragma unroll
    for (int j = 0; j < 4; j++) {
        float b1v = b1[e * DFF + nb * TN + wn + 16 * j + lr];
        #pragma unroll
        for (int i = 0; i < 4; i++)
            #pragma unroll
            for (int rr = 0; rr < 4; rr++)
                scr[(16 * i + crow + rr) * LDT + 16 * j + lr] = f2bf(gelu_exact(acc[i][j][rr] + b1v));
    }
    __syncthreads();
    int lh = l >> 3, ll = l & 7;
    #pragma unroll
    for (int k = 0; k < 8; k++) {
        uint4 v = *(const uint4*)&scr[(8 * k + lh) * LDT + ll * 8];
        int grow = hb + wm + 8 * k + lh;
        *(uint4*)&hbuf[(size_t)grow * DFF + nb * TN + wn + ll * 8] = v;
    }
}

// GEMM2: out[rtok[row], n] += rwgt[row] * ( hbuf[row, :] @ W2t[e][n, :] + b2[e][n] )
__global__ __launch_bounds__(256) void gemm2_kernel(
    const unsigned short* __restrict__ hbuf,
    const unsigned short* __restrict__ W2t,   // [E][HD][DFF] n-major
    const float* __restrict__ b2,
    const int* __restrict__ seg_count, const int* __restrict__ off_g,
    const int* __restrict__ rtok, const float* __restrict__ rwgt,
    float* __restrict__ out)
{
    int bid = blockIdx.x;
    int e   = bid & 7;
    int r2  = bid >> 3;
    int nb  = r2 & (HD / TN - 1);
    int mb  = r2 >> 2;
    int cnt = seg_count[e];
    if (mb * TM >= cnt) return;
    int hb = off_g[e] + mb * TM;

    __shared__ unsigned short smem[2 * BUFSZ];
    __shared__ int   tok_s[TM];
    __shared__ float wgt_s[TM];

    int tid = threadIdx.x;
    if (tid < TM) { tok_s[tid] = rtok[hb + tid]; wgt_s[tid] = rwgt[hb + tid]; }
    __syncthreads();

    int w = tid >> 6, l = tid & 63;
    int lr = l & 15, lk = (l >> 4) * 8, crow = (l >> 4) * 4;
    int wm = (w & 1) * 64, wn = (w >> 1) * 64;

    const unsigned short* w2e = W2t + (size_t)e * HD * DFF + (size_t)(nb * TN) * DFF;

    floatx4 acc[4][4];
    #pragma unroll
    for (int i = 0; i < 4; i++)
        #pragma unroll
        for (int j = 0; j < 4; j++) acc[i][j] = (floatx4){0.f, 0.f, 0.f, 0.f};

    int sr = tid >> 1, sh = (tid & 1) * 32;
    const uint4* ga = (const uint4*)(hbuf + (size_t)(hb + sr) * DFF + sh);  // row stride 256 uint4
    const uint4* gb4 = (const uint4*)(w2e + (size_t)sr * DFF + sh);
    int sofs = sr * LDT + sh;

    uint4 ra[4], rb[4];
    #pragma unroll
    for (int i = 0; i < 4; i++) { ra[i] = ga[i]; rb[i] = gb4[i]; }
    {
        uint4* da = (uint4*)&smem[sofs];
        uint4* db = (uint4*)&smem[TILE + sofs];
        #pragma unroll
        for (int i = 0; i < 4; i++) { da[i] = ra[i]; db[i] = rb[i]; }
    }
    __syncthreads();

    int buf = 0;
    for (int k0 = 0; k0 < DFF; k0 += BK) {
        int nk = k0 + BK;
        if (nk < DFF) {
            int o = nk >> 3;
            #pragma unroll
            for (int i = 0; i < 4; i++) { ra[i] = ga[o + i]; rb[i] = gb4[o + i]; }
        }
        const unsigned short* A = smem + buf * BUFSZ;
        const unsigned short* B = A + TILE;
        #pragma unroll
        for (int ks = 0; ks < BK; ks += 32) {
            bf16x8 a[4], b[4];
            #pragma unroll
            for (int i = 0; i < 4; i++) a[i] = *(const bf16x8*)&A[(wm + 16 * i + lr) * LDT + ks + lk];
            #pragma unroll
            for (int j = 0; j < 4; j++) b[j] = *(const bf16x8*)&B[(wn + 16 * j + lr) * LDT + ks + lk];
            #pragma unroll
            for (int i = 0; i < 4; i++)
                #pragma unroll
                for (int j = 0; j < 4; j++)
                    acc[i][j] = __builtin_amdgcn_mfma_f32_16x16x32_bf16(a[i], b[j], acc[i][j], 0, 0, 0);
        }
        if (nk < DFF) {
            buf ^= 1;
            uint4* da = (uint4*)&smem[buf * BUFSZ + sofs];
            uint4* db = (uint4*)&smem[buf * BUFSZ + TILE + sofs];
            #pragma unroll
            for (int i = 0; i < 4; i++) { da[i] = ra[i]; db[i] = rb[i]; }
            __syncthreads();
        }
    }

    // epilogue: +b2, x gate weight, atomicAdd (2 adds/element total across experts)
    #pragma unroll
    for (int j = 0; j < 4; j++) {
        int n = nb * TN + wn + 16 * j + lr;
        float b2v = b2[e * HD + n];
        #pragma unroll
        for (int i = 0; i < 4; i++)
            #pragma unroll
            for (int rr = 0; rr < 4; rr++) {
                int m = wm + 16 * i + crow + rr;
                atomicAdd(&out[(size_t)tok_s[m] * HD + n], (acc[i][j][rr] + b2v) * wgt_s[m]);
            }
    }
}

// ---------------- fused fallback (ws too small): R2-style, ZN=1, swizzled ----------------
#define BMT 64
#define FK  64
#define XS_LD 520
#define HS_LD 72

__global__ __launch_bounds__(256, 2) void ffn_fused_fallback(
    const unsigned short* __restrict__ xb,
    const unsigned short* __restrict__ W1t, const float* __restrict__ b1,
    const unsigned short* __restrict__ W2t, const float* __restrict__ b2,
    const int* __restrict__ seg_count, const int* __restrict__ seg_token,
    const float* __restrict__ seg_w, float* __restrict__ out)
{
    int bid = blockIdx.x;
    int e = bid & 7;
    int g = bid >> 3;
    int cnt = seg_count[e];
    int n0 = g * BMT;
    if (n0 >= cnt) return;
    int rows = min(BMT, cnt - n0);

    __shared__ unsigned short xs[BMT * XS_LD];
    __shared__ unsigned short hs[BMT * HS_LD];
    __shared__ int   tok_s[BMT];
    __shared__ float wgt_s[BMT];

    int tid = threadIdx.x;
    if (tid < BMT) {
        int idx = (tid < rows) ? (n0 + tid) : n0;
        tok_s[tid] = seg_token[e * TOK + idx];
        wgt_s[tid] = (tid < rows) ? seg_w[e * TOK + idx] : 0.f;
    }
    __syncthreads();
    {
        int r = tid >> 2, q = tid & 3;
        const uint4* src = (const uint4*)(xb + (size_t)tok_s[r] * HD) + q * 16;
        uint4* dst = (uint4*)&xs[(size_t)r * XS_LD + q * 128];
        #pragma unroll
        for (int i = 0; i < 16; i++) dst[i] = src[i];
    }
    __syncthreads();

    int w = tid >> 6, l = tid & 63;
    int lr = l & 15, lk = (l >> 4) * 8, crow = (l >> 4) * 4;

    const unsigned short* w1e = W1t + (size_t)e * DFF * HD;
    const unsigned short* w2e = W2t + (size_t)e * HD * DFF;

    floatx4 acc2[4][8];
    #pragma unroll
    for (int i = 0; i < 4; i++)
        #pragma unroll
        for (int j = 0; j < 8; j++) acc2[i][j] = (floatx4){0.f, 0.f, 0.f, 0.f};

    for (int fc = 0; fc < DFF; fc += FK) {
        floatx4 acc1[4];
        #pragma unroll
        for (int t = 0; t < 4; t++) acc1[t] = (floatx4){0.f, 0.f, 0.f, 0.f};
        const unsigned short* w1c = w1e + (size_t)fc * HD;
        for (int ks = 0; ks < HD; ks += 32) {
            bf16x8 a = *(const bf16x8*)&xs[(16 * w + lr) * XS_LD + ks + lk];
            #pragma unroll
            for (int t = 0; t < 4; t++) {
                bf16x8 b = *(const bf16x8*)(w1c + (size_t)(16 * t + lr) * HD + ks + lk);
                acc1[t] = __builtin_amdgcn_mfma_f32_16x16x32_bf16(a, b, acc1[t], 0, 0, 0);
            }
        }
        __syncthreads();
        #pragma unroll
        for (int t = 0; t < 4; t++) {
            float b1v = b1[e * DFF + fc + 16 * t + lr];
            #pragma unroll
            for (int r = 0; r < 4; r++)
                hs[(16 * w + crow + r) * HS_LD + 16 * t + lr] = f2bf(gelu_exact(acc1[t][r] + b1v));
        }
        __syncthreads();
        #pragma unroll
        for (int ks = 0; ks < FK; ks += 32) {
            bf16x8 af[4];
            #pragma unroll
            for (int i = 0; i < 4; i++) af[i] = *(const bf16x8*)&hs[(16 * i + lr) * HS_LD + ks + lk];
            #pragma unroll 4
            for (int j = 0; j < 8; j++) {
                bf16x8 b = *(const bf16x8*)(w2e + (size_t)(128 * w + 16 * j + lr) * DFF + fc + ks + lk);
                #pragma unroll
                for (int i = 0; i < 4; i++)
                    acc2[i][j] = __builtin_amdgcn_mfma_f32_16x16x32_bf16(af[i], b, acc2[i][j], 0, 0, 0);
            }
        }
    }
    #pragma unroll
    for (int j = 0; j < 8; j++) {
        int n = 128 * w + 16 * j + lr;
        float b2v = b2[e * HD + n];
        #pragma unroll
        for (int i = 0; i < 4; i++)
            #pragma unroll
            for (int r = 0; r < 4; r++) {
                int m = 16 * i + crow + r;
                atomicAdd(&out[(size_t)tok_s[m] * HD + n], (acc2[i][j][r] + b2v) * wgt_s[m]);
            }
    }
}

extern "C" void kernel_launch(void* const* d_in, const int* in_sizes, int n_in,
                              void* d_out, int out_size, void* d_ws, size_t ws_size,
                              hipStream_t stream)
{
    const float* x  = (const float*)d_in[0];
    const float* gW = (const float*)d_in[1];
    const float* gb = (const float*)d_in[2];
    const float* W1 = (const float*)d_in[3];
    const float* b1 = (const float*)d_in[4];
    const float* W2 = (const float*)d_in[5];
    const float* b2 = (const float*)d_in[6];
    float* out = (float*)d_out;

    // workspace layout (bytes)
    char* ws = (char*)d_ws;
    int*   seg_count = (int*)ws;                          // 32 B
    float* probs_sum = (float*)(ws + 32);                 // 32 B
    int*   off_g     = (int*)(ws + 128);                  // 36 B
    int*   rtok      = (int*)(ws + 1024);                 // 17408*4
    float* rwgt      = (float*)(ws + 1024 + 17408 * 4);
    int*   seg_token = (int*)(ws + 262144);               // NE*TOK*4
    float* seg_w     = (float*)(ws + 262144 + (size_t)NE * TOK * 4);
    unsigned short* xb   = (unsigned short*)(ws + (1u  << 20));  //  8 MiB
    unsigned short* W1t  = (unsigned short*)(ws + (16u << 20));  // 16 MiB
    unsigned short* W2t  = (unsigned short*)(ws + (32u << 20));  // 16 MiB
    unsigned short* hbuf = (unsigned short*)(ws + (48u << 20));  // 71.3 MB

    const size_t WS_SPLIT = (size_t)(48u << 20) + (size_t)17408 * DFF * 2;  // ~122 MB

    hipMemsetAsync(d_ws, 0, 64, stream);
    hipMemsetAsync(d_out, 0, (size_t)TOK * HD * sizeof(float), stream);

    gate_kernel<<<TOK / 256, 256, 0, stream>>>(x, gW, gb, seg_count, probs_sum,
                                               seg_token, seg_w, xb);
    finalize_kernel<<<1, 64, 0, stream>>>(seg_count, probs_sum, out + (size_t)TOK * HD);

    transpose_both_kernel<<<dim3(DFF / 64, HD / 64, 2 * NE), 256, 0, stream>>>(W1, W2, W1t, W2t);

    if (ws_size >= WS_SPLIT) {
        prefix_gather_kernel<<<68, 256, 0, stream>>>(seg_count, seg_token, seg_w,
                                                     off_g, rtok, rwgt);
        gemm1_kernel<<<NE * 64 * (DFF / TN), 256, 0, stream>>>(
            xb, W1t, b1, seg_count, off_g, rtok, hbuf);
        gemm2_kernel<<<NE * 64 * (HD / TN), 256, 0, stream>>>(
            hbuf, W2t, b2, seg_count, off_g, rtok, rwgt, out);
    } else {
        ffn_fused_fallback<<<(TOK / BMT) * NE, 256, 0, stream>>>(
            xb, W1t, b1, W2t, b2, seg_count, seg_token, seg_w, out);
    }
}

// Round 8
// 393.412 us; speedup vs baseline: 1.6332x; 1.6332x over previous
//
#include <hip/hip_runtime.h>
#include <math.h>

#define TOK 8192   // B*S tokens
#define HD  512    // hidden
#define NE  8      // experts
#define DFF 2048   // ffn dim

// ---------- bf16 helpers ----------
typedef __attribute__((ext_vector_type(8))) short bf16x8;
typedef __attribute__((ext_vector_type(4))) float floatx4;

__device__ inline unsigned short f2bf(float f) {
    union { float f; unsigned u; } v; v.f = f;
    unsigned r = v.u + 0x7FFFu + ((v.u >> 16) & 1u);   // round-nearest-even
    return (unsigned short)(r >> 16);
}

__device__ inline float gelu_exact(float v) {
    return 0.5f * v * (1.f + erff(v * 0.70710678118654752f));
}

// ---------- async global->LDS (16 B per lane; LDS dst = wave-uniform base + lane*16) ----------
typedef __attribute__((address_space(1))) const unsigned int glb_u32;
typedef __attribute__((address_space(3))) unsigned int lds_u32;
__device__ __forceinline__ void gload16(const unsigned short* g, unsigned short* l) {
    __builtin_amdgcn_global_load_lds((glb_u32*)g, (lds_u32*)l, 16, 0, 0);
}

// ---------------- gating (fp32, exact) + fused x->bf16 conversion ----------------
__global__ __launch_bounds__(256) void gate_kernel(
    const float* __restrict__ x, const float* __restrict__ gW, const float* __restrict__ gb,
    int* __restrict__ seg_count, float* __restrict__ probs_sum,
    int* __restrict__ seg_token, float* __restrict__ seg_w,
    unsigned short* __restrict__ xb)
{
    __shared__ float sW[HD * NE];
    __shared__ float psum[NE];
    __shared__ int   lcount[NE];
    __shared__ int   lbase[NE];

    int tid = threadIdx.x;
    for (int i = tid; i < HD * NE; i += 256) sW[i] = gW[i];
    if (tid < NE) { psum[tid] = 0.f; lcount[tid] = 0; }
    __syncthreads();

    int t = blockIdx.x * 256 + tid;
    float logit[NE];
    #pragma unroll
    for (int e = 0; e < NE; e++) logit[e] = gb[e];

    const float4* xr4 = reinterpret_cast<const float4*>(x + (size_t)t * HD);
    ushort4* xbw = reinterpret_cast<ushort4*>(xb + (size_t)t * HD);
    for (int j4 = 0; j4 < HD / 4; j4++) {
        float4 xv = xr4[j4];
        int j = j4 * 4;
        ushort4 o; o.x = f2bf(xv.x); o.y = f2bf(xv.y); o.z = f2bf(xv.z); o.w = f2bf(xv.w);
        xbw[j4] = o;
        #pragma unroll
        for (int e = 0; e < NE; e++) {
            logit[e] += xv.x * sW[(j + 0) * NE + e] + xv.y * sW[(j + 1) * NE + e]
                      + xv.z * sW[(j + 2) * NE + e] + xv.w * sW[(j + 3) * NE + e];
        }
    }

    float mx = logit[0];
    #pragma unroll
    for (int e = 1; e < NE; e++) mx = fmaxf(mx, logit[e]);
    float pe[NE]; float s = 0.f;
    #pragma unroll
    for (int e = 0; e < NE; e++) { pe[e] = expf(logit[e] - mx); s += pe[e]; }
    float inv = 1.f / s;
    int l = tid & 63;
    #pragma unroll
    for (int e = 0; e < NE; e++) {          // wave-shuffle reduce, 1 LDS atomic per wave per e
        float v = pe[e] * inv;
        for (int off = 32; off; off >>= 1) v += __shfl_down(v, off);
        if (l == 0) atomicAdd(&psum[e], v);
    }

    // top-2, lowest-index tie break (matches jax.lax.top_k)
    int i0 = 0; float v0 = logit[0];
    #pragma unroll
    for (int e = 1; e < NE; e++) if (logit[e] > v0) { v0 = logit[e]; i0 = e; }
    int i1 = -1; float v1 = -3.4e38f;
    #pragma unroll
    for (int e = 0; e < NE; e++) if (e != i0 && logit[e] > v1) { v1 = logit[e]; i1 = e; }
    float e1 = expf(v1 - v0);
    float w0 = 1.f / (1.f + e1);
    float w1 = e1 / (1.f + e1);

    int r0 = atomicAdd(&lcount[i0], 1);
    int r1 = atomicAdd(&lcount[i1], 1);
    __syncthreads();
    if (tid < NE) lbase[tid] = atomicAdd(&seg_count[tid], lcount[tid]);
    __syncthreads();
    int p0 = lbase[i0] + r0;
    seg_token[i0 * TOK + p0] = t; seg_w[i0 * TOK + p0] = w0;
    int p1 = lbase[i1] + r1;
    seg_token[i1 * TOK + p1] = t; seg_w[i1 * TOK + p1] = w1;

    __syncthreads();
    if (tid < NE) atomicAdd(&probs_sum[tid], psum[tid]);
}

// ---------------- l_aux + counts ----------------
__global__ void finalize_kernel(const int* __restrict__ seg_count,
                                const float* __restrict__ probs_sum,
                                float* __restrict__ out_tail)
{
    int tid = threadIdx.x;
    __shared__ float p2[NE];
    if (tid < NE) {
        float p = probs_sum[tid] * (1.f / (float)TOK);
        p2[tid] = p * p;
        out_tail[1 + tid] = (float)seg_count[tid];
    }
    __syncthreads();
    if (tid == 0) {
        float ssum = 0.f;
        #pragma unroll
        for (int e = 0; e < NE; e++) ssum += p2[e];
        out_tail[0] = ssum * (float)NE;
    }
}

// ---------------- weight transpose (both W1 and W2 in one launch) ----------------
__global__ __launch_bounds__(256) void transpose_both_kernel(
    const float* __restrict__ W1, const float* __restrict__ W2,
    unsigned short* __restrict__ W1t, unsigned short* __restrict__ W2t)
{
    __shared__ float tile[64][65];
    int z = blockIdx.z;
    const float* src; unsigned short* dst; int C, R, cb, rb;
    if (z < NE) {
        src = W1 + (size_t)z * HD * DFF; dst = W1t + (size_t)z * HD * DFF;
        R = HD; C = DFF; cb = blockIdx.x; rb = blockIdx.y;
    } else {
        int e = z - NE;
        src = W2 + (size_t)e * DFF * HD; dst = W2t + (size_t)e * DFF * HD;
        R = DFF; C = HD; cb = blockIdx.y; rb = blockIdx.x;
    }
    int c0 = cb * 64, r0 = rb * 64;
    int lc = threadIdx.x & 63, lrw = threadIdx.x >> 6;
    #pragma unroll
    for (int rr = lrw; rr < 64; rr += 4)
        tile[rr][lc] = src[(size_t)(r0 + rr) * C + c0 + lc];
    __syncthreads();
    #pragma unroll
    for (int cc = lrw; cc < 64; cc += 4)
        dst[(size_t)(c0 + cc) * R + r0 + lc] = f2bf(tile[lc][cc]);
}

// ---------------- prefix + gather (parallel): 128-padded per-expert row segments ----------------
#define RPAD 128
__global__ void prefix_gather_kernel(const int* __restrict__ seg_count,
                                     const int* __restrict__ seg_token,
                                     const float* __restrict__ seg_w,
                                     int* __restrict__ off_g,
                                     int* __restrict__ rtok, float* __restrict__ rwgt)
{
    __shared__ int off_s[NE + 1];
    if (threadIdx.x == 0) {
        int acc = 0;
        #pragma unroll
        for (int e = 0; e < NE; e++) {
            off_s[e] = acc;
            if (blockIdx.x == 0) off_g[e] = acc;
            acc += ((seg_count[e] + RPAD - 1) / RPAD) * RPAD;
        }
        off_s[NE] = acc;
        if (blockIdx.x == 0) off_g[NE] = acc;
    }
    __syncthreads();
    int total = off_s[NE];
    int i = blockIdx.x * 256 + threadIdx.x;
    if (i >= total) return;
    int e = 0;
    #pragma unroll
    for (int ee = 0; ee < NE; ee++) if (i >= off_s[ee + 1]) e = ee + 1;
    int li = i - off_s[e];
    int cnt = seg_count[e];
    if (li < cnt) { rtok[i] = seg_token[e * TOK + li]; rwgt[i] = seg_w[e * TOK + li]; }
    else          { rtok[i] = seg_token[e * TOK];      rwgt[i] = 0.f; }   // pad: dup row0, weight 0
}

// ---------------- split GEMM path: m97 structure ----------------
// 128x128 tiles, BK=64, 4 waves x 64x64. Single-buffered LDS, 2 barriers/iter,
// global->LDS via async DMA (no staging VGPRs). LDS rows are unpadded 64 ushorts
// (DMA requires dst = base + lane*16); bank conflicts broken by XOR swizzle:
// 16B group at (row, kg) lives at slot kg ^ (row & 7).
#define TM  128
#define TN  128
#define BK  64

// GEMM1: hbuf[row, n] = gelu( xb[rtok[row], :] @ W1t[e][n, :] + b1[e][n] )
__global__ __launch_bounds__(256) void gemm1_kernel(
    const unsigned short* __restrict__ xb,
    const unsigned short* __restrict__ W1t,   // [E][DFF][HD] n-major
    const float* __restrict__ b1,
    const int* __restrict__ seg_count, const int* __restrict__ off_g,
    const int* __restrict__ rtok,
    unsigned short* __restrict__ hbuf)        // [rows][DFF]
{
    int bid = blockIdx.x;
    int e   = bid & 7;                         // low bits -> XCD affinity
    int r2  = bid >> 3;
    int nb  = r2 & (DFF / TN - 1);
    int mb  = r2 >> 4;
    int cnt = seg_count[e];
    if (mb * TM >= cnt) return;
    int hb = off_g[e] + mb * TM;

    __shared__ __align__(16) unsigned short smem[18432]; // As 8192 | Bs 8192; epi scratch 4*64*72
    unsigned short* As = smem;
    unsigned short* Bs = smem + 8192;
    __shared__ int tok_s[TM];

    int tid = threadIdx.x;
    if (tid < TM) tok_s[tid] = rtok[hb + tid];
    __syncthreads();

    int w = tid >> 6, l = tid & 63;
    int lr = l & 15, crow = (l >> 4) * 4;
    int wm = (w & 1) * 64, wn = (w >> 1) * 64;

    const unsigned short* w1e = W1t + (size_t)e * DFF * HD + (size_t)(nb * TN) * HD;

    // staging: wave w covers rows w*32..w*32+32 in 4 slots of 8 rows; lane l -> row +(l>>3),
    // global 16B-group c8 = (l&7) ^ (row&7) so it lands at LDS slot l (swizzle-consistent).
    int srow = w * 32 + (l >> 3);
    int c8   = (l & 7) ^ ((l >> 3) & 7);
    unsigned aofs[4], bofs[4];
    #pragma unroll
    for (int s = 0; s < 4; s++) {
        int r = srow + 8 * s;
        aofs[s] = (unsigned)tok_s[r] * HD + (unsigned)(c8 * 8);
        bofs[s] = (unsigned)(r * HD) + (unsigned)(c8 * 8);
    }
    // fragment-read swizzle slot (ushort offset): depends only on (ks, lane)
    int slot0 = (((l >> 4) ^ (lr & 7)) << 3);   // ks=0
    int slot1 = slot0 ^ 32;                     // ks=32  (q^4 == q+4 for q<4)

    floatx4 acc[4][4];
    #pragma unroll
    for (int i = 0; i < 4; i++)
        #pragma unroll
        for (int j = 0; j < 4; j++) acc[i][j] = (floatx4){0.f, 0.f, 0.f, 0.f};

    for (int k0 = 0; k0 < HD; k0 += BK) {
        #pragma unroll
        for (int s = 0; s < 4; s++) {
            gload16(xb  + aofs[s] + k0, &As[(w * 32 + 8 * s) * 64]);
            gload16(w1e + bofs[s] + k0, &Bs[(w * 32 + 8 * s) * 64]);
        }
        __syncthreads();
        #pragma unroll
        for (int ks = 0; ks < 2; ks++) {
            int slot = ks ? slot1 : slot0;
            bf16x8 a[4], b[4];
            #pragma unroll
            for (int i = 0; i < 4; i++) a[i] = *(const bf16x8*)&As[(wm + 16 * i + lr) * 64 + slot];
            #pragma unroll
            for (int j = 0; j < 4; j++) b[j] = *(const bf16x8*)&Bs[(wn + 16 * j + lr) * 64 + slot];
            #pragma unroll
            for (int i = 0; i < 4; i++)
                #pragma unroll
                for (int j = 0; j < 4; j++)
                    acc[i][j] = __builtin_amdgcn_mfma_f32_16x16x32_bf16(a[i], b[j], acc[i][j], 0, 0, 0);
        }
        __syncthreads();
    }

    // epilogue: +b1, gelu, bf16 -> per-wave LDS scratch (LD 72) -> coalesced 16B stores
    unsigned short* scr = smem + w * 64 * 72;
    #pragma unroll
    for (int j = 0; j < 4; j++) {
        float b1v = b1[e * DFF + nb * TN + wn + 16 * j + lr];
        #pragma unroll
        for (int i = 0; i < 4; i++)
            #pragma unroll
            for (int rr = 0; rr < 4; rr++)
                scr[(16 * i + crow + rr) * 72 + 16 * j + lr] = f2bf(gelu_exact(acc[i][j][rr] + b1v));
    }
    __syncthreads();
    int lh = l >> 3, ll = l & 7;
    #pragma unroll
    for (int k = 0; k < 8; k++) {
        uint4 v = *(const uint4*)&scr[(8 * k + lh) * 72 + ll * 8];
        int grow = hb + wm + 8 * k + lh;
        *(uint4*)&hbuf[(size_t)grow * DFF + nb * TN + wn + ll * 8] = v;
    }
}

// GEMM2: out[rtok[row], n] += rwgt[row] * ( hbuf[row, :] @ W2t[e][n, :] + b2[e][n] )
__global__ __launch_bounds__(256) void gemm2_kernel(
    const unsigned short* __restrict__ hbuf,
    const unsigned short* __restrict__ W2t,   // [E][HD][DFF] n-major
    const float* __restrict__ b2,
    const int* __restrict__ seg_count, const int* __restrict__ off_g,
    const int* __restrict__ rtok, const float* __restrict__ rwgt,
    float* __restrict__ out)
{
    int bid = blockIdx.x;
    int e   = bid & 7;
    int r2  = bid >> 3;
    int nb  = r2 & (HD / TN - 1);
    int mb  = r2 >> 2;
    int cnt = seg_count[e];
    if (mb * TM >= cnt) return;
    int hb = off_g[e] + mb * TM;

    __shared__ __align__(16) unsigned short smem[16384];  // As 8192 | Bs 8192
    unsigned short* As = smem;
    unsigned short* Bs = smem + 8192;
    __shared__ int   tok_s[TM];
    __shared__ float wgt_s[TM];

    int tid = threadIdx.x;
    if (tid < TM) { tok_s[tid] = rtok[hb + tid]; wgt_s[tid] = rwgt[hb + tid]; }
    __syncthreads();

    int w = tid >> 6, l = tid & 63;
    int lr = l & 15, crow = (l >> 4) * 4;
    int wm = (w & 1) * 64, wn = (w >> 1) * 64;

    const unsigned short* w2e = W2t + (size_t)e * HD * DFF + (size_t)(nb * TN) * DFF;

    int srow = w * 32 + (l >> 3);
    int c8   = (l & 7) ^ ((l >> 3) & 7);
    unsigned aofs[4], bofs[4];
    #pragma unroll
    for (int s = 0; s < 4; s++) {
        int r = srow + 8 * s;
        aofs[s] = (unsigned)((hb + r) * DFF) + (unsigned)(c8 * 8);
        bofs[s] = (unsigned)(r * DFF) + (unsigned)(c8 * 8);
    }
    int slot0 = (((l >> 4) ^ (lr & 7)) << 3);
    int slot1 = slot0 ^ 32;

    floatx4 acc[4][4];
    #pragma unroll
    for (int i = 0; i < 4; i++)
        #pragma unroll
        for (int j = 0; j < 4; j++) acc[i][j] = (floatx4){0.f, 0.f, 0.f, 0.f};

    for (int k0 = 0; k0 < DFF; k0 += BK) {
        #pragma unroll
        for (int s = 0; s < 4; s++) {
            gload16(hbuf + aofs[s] + k0, &As[(w * 32 + 8 * s) * 64]);
            gload16(w2e  + bofs[s] + k0, &Bs[(w * 32 + 8 * s) * 64]);
        }
        __syncthreads();
        #pragma unroll
        for (int ks = 0; ks < 2; ks++) {
            int slot = ks ? slot1 : slot0;
            bf16x8 a[4], b[4];
            #pragma unroll
            for (int i = 0; i < 4; i++) a[i] = *(const bf16x8*)&As[(wm + 16 * i + lr) * 64 + slot];
            #pragma unroll
            for (int j = 0; j < 4; j++) b[j] = *(const bf16x8*)&Bs[(wn + 16 * j + lr) * 64 + slot];
            #pragma unroll
            for (int i = 0; i < 4; i++)
                #pragma unroll
                for (int j = 0; j < 4; j++)
                    acc[i][j] = __builtin_amdgcn_mfma_f32_16x16x32_bf16(a[i], b[j], acc[i][j], 0, 0, 0);
        }
        __syncthreads();
    }

    // epilogue: +b2, x gate weight, atomicAdd (2 adds/element total across experts)
    #pragma unroll
    for (int j = 0; j < 4; j++) {
        int n = nb * TN + wn + 16 * j + lr;
        float b2v = b2[e * HD + n];
        #pragma unroll
        for (int i = 0; i < 4; i++)
            #pragma unroll
            for (int rr = 0; rr < 4; rr++) {
                int m = wm + 16 * i + crow + rr;
                atomicAdd(&out[(size_t)tok_s[m] * HD + n], (acc[i][j][rr] + b2v) * wgt_s[m]);
            }
    }
}

// ---------------- fused fallback (ws too small): R2-style, swizzled ----------------
#define BMT 64
#define FK  64
#define XS_LD 520
#define HS_LD 72

__global__ __launch_bounds__(256, 2) void ffn_fused_fallback(
    const unsigned short* __restrict__ xb,
    const unsigned short* __restrict__ W1t, const float* __restrict__ b1,
    const unsigned short* __restrict__ W2t, const float* __restrict__ b2,
    const int* __restrict__ seg_count, const int* __restrict__ seg_token,
    const float* __restrict__ seg_w, float* __restrict__ out)
{
    int bid = blockIdx.x;
    int e = bid & 7;
    int g = bid >> 3;
    int cnt = seg_count[e];
    int n0 = g * BMT;
    if (n0 >= cnt) return;
    int rows = min(BMT, cnt - n0);

    __shared__ unsigned short xs[BMT * XS_LD];
    __shared__ unsigned short hs[BMT * HS_LD];
    __shared__ int   tok_s[BMT];
    __shared__ float wgt_s[BMT];

    int tid = threadIdx.x;
    if (tid < BMT) {
        int idx = (tid < rows) ? (n0 + tid) : n0;
        tok_s[tid] = seg_token[e * TOK + idx];
        wgt_s[tid] = (tid < rows) ? seg_w[e * TOK + idx] : 0.f;
    }
    __syncthreads();
    {
        int r = tid >> 2, q = tid & 3;
        const uint4* src = (const uint4*)(xb + (size_t)tok_s[r] * HD) + q * 16;
        uint4* dst = (uint4*)&xs[(size_t)r * XS_LD + q * 128];
        #pragma unroll
        for (int i = 0; i < 16; i++) dst[i] = src[i];
    }
    __syncthreads();

    int w = tid >> 6, l = tid & 63;
    int lr = l & 15, lk = (l >> 4) * 8, crow = (l >> 4) * 4;

    const unsigned short* w1e = W1t + (size_t)e * DFF * HD;
    const unsigned short* w2e = W2t + (size_t)e * HD * DFF;

    floatx4 acc2[4][8];
    #pragma unroll
    for (int i = 0; i < 4; i++)
        #pragma unroll
        for (int j = 0; j < 8; j++) acc2[i][j] = (floatx4){0.f, 0.f, 0.f, 0.f};

    for (int fc = 0; fc < DFF; fc += FK) {
        floatx4 acc1[4];
        #pragma unroll
        for (int t = 0; t < 4; t++) acc1[t] = (floatx4){0.f, 0.f, 0.f, 0.f};
        const unsigned short* w1c = w1e + (size_t)fc * HD;
        for (int ks = 0; ks < HD; ks += 32) {
            bf16x8 a = *(const bf16x8*)&xs[(16 * w + lr) * XS_LD + ks + lk];
            #pragma unroll
            for (int t = 0; t < 4; t++) {
                bf16x8 b = *(const bf16x8*)(w1c + (size_t)(16 * t + lr) * HD + ks + lk);
                acc1[t] = __builtin_amdgcn_mfma_f32_16x16x32_bf16(a, b, acc1[t], 0, 0, 0);
            }
        }
        __syncthreads();
        #pragma unroll
        for (int t = 0; t < 4; t++) {
            float b1v = b1[e * DFF + fc + 16 * t + lr];
            #pragma unroll
            for (int r = 0; r < 4; r++)
                hs[(16 * w + crow + r) * HS_LD + 16 * t + lr] = f2bf(gelu_exact(acc1[t][r] + b1v));
        }
        __syncthreads();
        #pragma unroll
        for (int ks = 0; ks < FK; ks += 32) {
            bf16x8 af[4];
            #pragma unroll
            for (int i = 0; i < 4; i++) af[i] = *(const bf16x8*)&hs[(16 * i + lr) * HS_LD + ks + lk];
            #pragma unroll 4
            for (int j = 0; j < 8; j++) {
                bf16x8 b = *(const bf16x8*)(w2e + (size_t)(128 * w + 16 * j + lr) * DFF + fc + ks + lk);
                #pragma unroll
                for (int i = 0; i < 4; i++)
                    acc2[i][j] = __builtin_amdgcn_mfma_f32_16x16x32_bf16(af[i], b, acc2[i][j], 0, 0, 0);
            }
        }
    }
    #pragma unroll
    for (int j = 0; j < 8; j++) {
        int n = 128 * w + 16 * j + lr;
        float b2v = b2[e * HD + n];
        #pragma unroll
        for (int i = 0; i < 4; i++)
            #pragma unroll
            for (int r = 0; r < 4; r++) {
                int m = 16 * i + crow + r;
                atomicAdd(&out[(size_t)tok_s[m] * HD + n], (acc2[i][j][r] + b2v) * wgt_s[m]);
            }
    }
}

extern "C" void kernel_launch(void* const* d_in, const int* in_sizes, int n_in,
                              void* d_out, int out_size, void* d_ws, size_t ws_size,
                              hipStream_t stream)
{
    const float* x  = (const float*)d_in[0];
    const float* gW = (const float*)d_in[1];
    const float* gb = (const float*)d_in[2];
    const float* W1 = (const float*)d_in[3];
    const float* b1 = (const float*)d_in[4];
    const float* W2 = (const float*)d_in[5];
    const float* b2 = (const float*)d_in[6];
    float* out = (float*)d_out;

    // workspace layout (bytes)
    char* ws = (char*)d_ws;
    int*   seg_count = (int*)ws;                          // 32 B
    float* probs_sum = (float*)(ws + 32);                 // 32 B
    int*   off_g     = (int*)(ws + 128);                  // 36 B
    int*   rtok      = (int*)(ws + 1024);                 // 17408*4
    float* rwgt      = (float*)(ws + 1024 + 17408 * 4);
    int*   seg_token = (int*)(ws + 262144);               // NE*TOK*4
    float* seg_w     = (float*)(ws + 262144 + (size_t)NE * TOK * 4);
    unsigned short* xb   = (unsigned short*)(ws + (1u  << 20));  //  8 MiB
    unsigned short* W1t  = (unsigned short*)(ws + (16u << 20));  // 16 MiB
    unsigned short* W2t  = (unsigned short*)(ws + (32u << 20));  // 16 MiB
    unsigned short* hbuf = (unsigned short*)(ws + (48u << 20));  // 71.3 MB

    const size_t WS_SPLIT = (size_t)(48u << 20) + (size_t)17408 * DFF * 2;  // ~122 MB

    hipMemsetAsync(d_ws, 0, 64, stream);
    hipMemsetAsync(d_out, 0, (size_t)TOK * HD * sizeof(float), stream);

    gate_kernel<<<TOK / 256, 256, 0, stream>>>(x, gW, gb, seg_count, probs_sum,
                                               seg_token, seg_w, xb);
    finalize_kernel<<<1, 64, 0, stream>>>(seg_count, probs_sum, out + (size_t)TOK * HD);

    transpose_both_kernel<<<dim3(DFF / 64, HD / 64, 2 * NE), 256, 0, stream>>>(W1, W2, W1t, W2t);

    if (ws_size >= WS_SPLIT) {
        prefix_gather_kernel<<<68, 256, 0, stream>>>(seg_count, seg_token, seg_w,
                                                     off_g, rtok, rwgt);
        gemm1_kernel<<<NE * 64 * (DFF / TN), 256, 0, stream>>>(
            xb, W1t, b1, seg_count, off_g, rtok, hbuf);
        gemm2_kernel<<<NE * 64 * (HD / TN), 256, 0, stream>>>(
            hbuf, W2t, b2, seg_count, off_g, rtok, rwgt, out);
    } else {
        ffn_fused_fallback<<<(TOK / BMT) * NE, 256, 0, stream>>>(
            xb, W1t, b1, W2t, b2, seg_count, seg_token, seg_w, out);
    }
}

// Round 9
// 351.224 us; speedup vs baseline: 1.8293x; 1.1201x over previous
//
#include <hip/hip_runtime.h>
#include <math.h>

#define TOK 8192   // B*S tokens
#define HD  512    // hidden
#define NE  8      // experts
#define DFF 2048   // ffn dim

// ---------- bf16 helpers ----------
typedef __attribute__((ext_vector_type(8))) short bf16x8;
typedef __attribute__((ext_vector_type(4))) float floatx4;

__device__ inline unsigned short f2bf(float f) {
    union { float f; unsigned u; } v; v.f = f;
    unsigned r = v.u + 0x7FFFu + ((v.u >> 16) & 1u);   // round-nearest-even
    return (unsigned short)(r >> 16);
}

__device__ inline float gelu_exact(float v) {
    return 0.5f * v * (1.f + erff(v * 0.70710678118654752f));
}

// ---------- async global->LDS (16 B/lane; LDS dst = wave-uniform base + lane*16) ----------
typedef __attribute__((address_space(1))) const unsigned int glb_u32;
typedef __attribute__((address_space(3))) unsigned int lds_u32;
__device__ __forceinline__ void gload16(const unsigned short* g, unsigned short* l) {
    __builtin_amdgcn_global_load_lds((glb_u32*)g, (lds_u32*)l, 16, 0, 0);
}

// ---------------- prep kernel: gate (32 blocks) + weight transpose (4096 blocks) ----------------
// Independent inputs -> fused into one launch so they run concurrently.
__global__ __launch_bounds__(256) void prep_kernel(
    const float* __restrict__ x, const float* __restrict__ gW, const float* __restrict__ gb,
    const float* __restrict__ W1, const float* __restrict__ W2,
    int* __restrict__ seg_count, float* __restrict__ probs_sum,
    int* __restrict__ seg_token, float* __restrict__ seg_w,
    unsigned short* __restrict__ xb,
    unsigned short* __restrict__ W1t, unsigned short* __restrict__ W2t)
{
    __shared__ __align__(16) char shraw[16896];
    int bid = blockIdx.x;
    int tid = threadIdx.x;

    if (bid >= 32) {
        // ---- transpose block: z<NE: W1 [e][HD][DFF]->W1t [e][DFF][HD]; else W2 -> W2t
        int b = bid - 32;
        float (*tile)[65] = (float(*)[65])shraw;
        int z = b >> 8, rem = b & 255;
        int xq = rem & 31, yq = rem >> 5;
        const float* src; unsigned short* dst; int C, R, cb, rb;
        if (z < NE) {
            src = W1 + (size_t)z * HD * DFF; dst = W1t + (size_t)z * HD * DFF;
            R = HD; C = DFF; cb = xq; rb = yq;
        } else {
            int e = z - NE;
            src = W2 + (size_t)e * DFF * HD; dst = W2t + (size_t)e * DFF * HD;
            R = DFF; C = HD; cb = yq; rb = xq;
        }
        int c0 = cb * 64, r0 = rb * 64;
        int lc = tid & 63, lrw = tid >> 6;
        #pragma unroll
        for (int rr = lrw; rr < 64; rr += 4)
            tile[rr][lc] = src[(size_t)(r0 + rr) * C + c0 + lc];
        __syncthreads();
        #pragma unroll
        for (int cc = lrw; cc < 64; cc += 4)
            dst[(size_t)(c0 + cc) * R + r0 + lc] = f2bf(tile[lc][cc]);
        return;
    }

    // ---- gate block (fp32 exact) + fused x->bf16 conversion
    float* sW    = (float*)shraw;             // 16384 B
    float* psum  = (float*)(shraw + 16384);   // 32 B
    int*   lcount = (int*)(shraw + 16448);
    int*   lbase  = (int*)(shraw + 16512);

    for (int i = tid; i < HD * NE; i += 256) sW[i] = gW[i];
    if (tid < NE) { psum[tid] = 0.f; lcount[tid] = 0; }
    __syncthreads();

    int t = bid * 256 + tid;
    float logit[NE];
    #pragma unroll
    for (int e = 0; e < NE; e++) logit[e] = gb[e];

    const float4* xr4 = reinterpret_cast<const float4*>(x + (size_t)t * HD);
    ushort4* xbw = reinterpret_cast<ushort4*>(xb + (size_t)t * HD);
    for (int j4 = 0; j4 < HD / 4; j4++) {
        float4 xv = xr4[j4];
        int j = j4 * 4;
        ushort4 o; o.x = f2bf(xv.x); o.y = f2bf(xv.y); o.z = f2bf(xv.z); o.w = f2bf(xv.w);
        xbw[j4] = o;
        #pragma unroll
        for (int e = 0; e < NE; e++) {
            logit[e] += xv.x * sW[(j + 0) * NE + e] + xv.y * sW[(j + 1) * NE + e]
                      + xv.z * sW[(j + 2) * NE + e] + xv.w * sW[(j + 3) * NE + e];
        }
    }

    float mx = logit[0];
    #pragma unroll
    for (int e = 1; e < NE; e++) mx = fmaxf(mx, logit[e]);
    float pe[NE]; float s = 0.f;
    #pragma unroll
    for (int e = 0; e < NE; e++) { pe[e] = expf(logit[e] - mx); s += pe[e]; }
    float inv = 1.f / s;
    int l = tid & 63;
    #pragma unroll
    for (int e = 0; e < NE; e++) {          // wave-shuffle reduce, 1 LDS atomic/wave/e
        float v = pe[e] * inv;
        for (int off = 32; off; off >>= 1) v += __shfl_down(v, off);
        if (l == 0) atomicAdd(&psum[e], v);
    }

    // top-2, lowest-index tie break (matches jax.lax.top_k)
    int i0 = 0; float v0 = logit[0];
    #pragma unroll
    for (int e = 1; e < NE; e++) if (logit[e] > v0) { v0 = logit[e]; i0 = e; }
    int i1 = -1; float v1 = -3.4e38f;
    #pragma unroll
    for (int e = 0; e < NE; e++) if (e != i0 && logit[e] > v1) { v1 = logit[e]; i1 = e; }
    float e1 = expf(v1 - v0);
    float w0 = 1.f / (1.f + e1);
    float w1 = e1 / (1.f + e1);

    int r0 = atomicAdd(&lcount[i0], 1);
    int r1 = atomicAdd(&lcount[i1], 1);
    __syncthreads();
    if (tid < NE) lbase[tid] = atomicAdd(&seg_count[tid], lcount[tid]);
    __syncthreads();
    int p0 = lbase[i0] + r0;
    seg_token[i0 * TOK + p0] = t; seg_w[i0 * TOK + p0] = w0;
    int p1 = lbase[i1] + r1;
    seg_token[i1 * TOK + p1] = t; seg_w[i1 * TOK + p1] = w1;

    __syncthreads();
    if (tid < NE) atomicAdd(&probs_sum[tid], psum[tid]);
}

// ---------------- split GEMM path: one-barrier pipelined K-loop ----------------
// 128x128 tiles, BK=64, 4 waves x 64x64. Double-buffered LDS fed by async DMA:
// per iter: [barrier drains DMA(k)] -> read 16 frags -> issue DMA(k+1) into the
// other buffer -> 32 MFMA. DMA gets a full compute section of flight time.
// Swizzle (R8-proven, 0 conflicts): LDS group g holds global group g^(row&7).
#define TM  128
#define TN  128
#define BK  64

// GEMM1: hbuf[row, n] = gelu( xb[seg_token[e][row], :] @ W1t[e][n, :] + b1[e][n] )
// Also: block 0 computes l_aux + expert_counts (folded finalize).
__global__ __launch_bounds__(256) void gemm1_kernel(
    const unsigned short* __restrict__ xb,
    const unsigned short* __restrict__ W1t,   // [E][DFF][HD] n-major
    const float* __restrict__ bias1,
    const int* __restrict__ seg_count, const float* __restrict__ probs_sum,
    const int* __restrict__ seg_token,
    unsigned short* __restrict__ hbuf,        // [rows][DFF]
    float* __restrict__ out_tail)
{
    int bid = blockIdx.x;
    int tid = threadIdx.x;

    if (bid == 0) {           // folded finalize
        if (tid < NE) out_tail[1 + tid] = (float)seg_count[tid];
        else if (tid == 64) {
            float s = 0.f;
            #pragma unroll
            for (int e2 = 0; e2 < NE; e2++) {
                float p = probs_sum[e2] * (1.f / (float)TOK);
                s += p * p;
            }
            out_tail[0] = s * (float)NE;
        }
    }

    int e  = bid & 7;                          // low bits -> XCD affinity
    int r2 = bid >> 3;
    int nb = r2 & 15;                          // DFF/TN = 16
    int mb = r2 >> 4;                          // 0..63
    int cnt = seg_count[e];
    if (mb * TM >= cnt) return;
    int off_e = 0;
    #pragma unroll
    for (int ee = 0; ee < NE; ee++) if (ee < e) off_e += (seg_count[ee] + 127) & ~127;
    int hb = off_e + mb * TM;

    __shared__ __align__(16) unsigned short smem[2][2][TM * 64];   // 65536 B
    __shared__ int tok_s[TM];
    if (tid < TM) {
        int gi = mb * TM + tid;
        tok_s[tid] = seg_token[e * TOK + ((gi < cnt) ? gi : 0)];   // pad: dup row0
    }
    __syncthreads();

    int w = tid >> 6, l = tid & 63;
    int lr = l & 15, crow = (l >> 4) * 4;
    int wm = (w & 1) * 64, wn = (w >> 1) * 64;
    const unsigned short* w1e = W1t + (size_t)e * DFF * HD + (size_t)(nb * TN) * HD;

    int srow = w * 32 + (l >> 3);
    int c8   = (l & 7) ^ ((l >> 3) & 7);
    unsigned aofs[4], bofs[4];
    #pragma unroll
    for (int s = 0; s < 4; s++) {
        int r = srow + 8 * s;
        aofs[s] = (unsigned)tok_s[r] * HD + (unsigned)(c8 * 8);
        bofs[s] = (unsigned)(r * HD) + (unsigned)(c8 * 8);
    }
    int slot0 = (((l >> 4) ^ (lr & 7)) << 3);
    int slot1 = slot0 ^ 32;

    floatx4 acc[4][4];
    #pragma unroll
    for (int i = 0; i < 4; i++)
        #pragma unroll
        for (int j = 0; j < 4; j++) acc[i][j] = (floatx4){0.f, 0.f, 0.f, 0.f};

    // prologue DMA -> buf 0
    #pragma unroll
    for (int s = 0; s < 4; s++) {
        gload16(xb  + aofs[s], &smem[0][0][(w * 32 + 8 * s) * 64]);
        gload16(w1e + bofs[s], &smem[0][1][(w * 32 + 8 * s) * 64]);
    }
    int buf = 0;
    for (int k0 = 0; k0 < HD; k0 += BK) {
        __syncthreads();                       // drains DMA(k0); protects buffers
        const unsigned short* A = smem[buf][0];
        const unsigned short* B = smem[buf][1];
        bf16x8 a0[4], b0[4], a1[4], b1f[4];
        #pragma unroll
        for (int i = 0; i < 4; i++) {
            a0[i]  = *(const bf16x8*)&A[(wm + 16 * i + lr) * 64 + slot0];
            a1[i]  = *(const bf16x8*)&A[(wm + 16 * i + lr) * 64 + slot1];
            b0[i]  = *(const bf16x8*)&B[(wn + 16 * i + lr) * 64 + slot0];
            b1f[i] = *(const bf16x8*)&B[(wn + 16 * i + lr) * 64 + slot1];
        }
        int nk = k0 + BK;
        if (nk < HD) {                         // issue next tile's DMA (other buffer)
            int nbf = buf ^ 1;
            #pragma unroll
            for (int s = 0; s < 4; s++) {
                gload16(xb  + aofs[s] + nk, &smem[nbf][0][(w * 32 + 8 * s) * 64]);
                gload16(w1e + bofs[s] + nk, &smem[nbf][1][(w * 32 + 8 * s) * 64]);
            }
        }
        #pragma unroll
        for (int i = 0; i < 4; i++)
            #pragma unroll
            for (int j = 0; j < 4; j++)
                acc[i][j] = __builtin_amdgcn_mfma_f32_16x16x32_bf16(a0[i], b0[j], acc[i][j], 0, 0, 0);
        #pragma unroll
        for (int i = 0; i < 4; i++)
            #pragma unroll
            for (int j = 0; j < 4; j++)
                acc[i][j] = __builtin_amdgcn_mfma_f32_16x16x32_bf16(a1[i], b1f[j], acc[i][j], 0, 0, 0);
        buf ^= 1;
    }
    __syncthreads();                           // done with buffers before scratch reuse

    // epilogue: +b1, gelu, bf16 -> per-wave LDS scratch (LD 72) -> coalesced 16B stores
    unsigned short* scr = &smem[0][0][0] + w * 64 * 72;
    #pragma unroll
    for (int j = 0; j < 4; j++) {
        float b1v = bias1[e * DFF + nb * TN + wn + 16 * j + lr];
        #pragma unroll
        for (int i = 0; i < 4; i++)
            #pragma unroll
            for (int rr = 0; rr < 4; rr++)
                scr[(16 * i + crow + rr) * 72 + 16 * j + lr] = f2bf(gelu_exact(acc[i][j][rr] + b1v));
    }
    __syncthreads();
    int lh = l >> 3, ll = l & 7;
    #pragma unroll
    for (int k = 0; k < 8; k++) {
        uint4 v = *(const uint4*)&scr[(8 * k + lh) * 72 + ll * 8];
        int grow = hb + wm + 8 * k + lh;
        *(uint4*)&hbuf[(size_t)grow * DFF + nb * TN + wn + ll * 8] = v;
    }
}

// GEMM2: out[seg_token[e][row], n] += seg_w[e][row] * ( hbuf[row, :] @ W2t[e][n, :] + b2[e][n] )
__global__ __launch_bounds__(256) void gemm2_kernel(
    const unsigned short* __restrict__ hbuf,
    const unsigned short* __restrict__ W2t,   // [E][HD][DFF] n-major
    const float* __restrict__ b2,
    const int* __restrict__ seg_count, const int* __restrict__ seg_token,
    const float* __restrict__ seg_w,
    float* __restrict__ out)
{
    int bid = blockIdx.x;
    int tid = threadIdx.x;
    int e  = bid & 7;
    int r2 = bid >> 3;
    int nb = r2 & 3;                           // HD/TN = 4
    int mb = r2 >> 2;                          // 0..63
    int cnt = seg_count[e];
    if (mb * TM >= cnt) return;
    int off_e = 0;
    #pragma unroll
    for (int ee = 0; ee < NE; ee++) if (ee < e) off_e += (seg_count[ee] + 127) & ~127;
    int hb = off_e + mb * TM;

    __shared__ __align__(16) unsigned short smem[2][2][TM * 64];   // 65536 B
    __shared__ int   tok_s[TM];
    __shared__ float wgt_s[TM];
    if (tid < TM) {
        int gi = mb * TM + tid;
        tok_s[tid] = seg_token[e * TOK + ((gi < cnt) ? gi : 0)];
        wgt_s[tid] = (gi < cnt) ? seg_w[e * TOK + gi] : 0.f;      // pad weight 0
    }
    __syncthreads();

    int w = tid >> 6, l = tid & 63;
    int lr = l & 15, crow = (l >> 4) * 4;
    int wm = (w & 1) * 64, wn = (w >> 1) * 64;
    const unsigned short* w2e = W2t + (size_t)e * HD * DFF + (size_t)(nb * TN) * DFF;

    int srow = w * 32 + (l >> 3);
    int c8   = (l & 7) ^ ((l >> 3) & 7);
    unsigned aofs[4], bofs[4];
    #pragma unroll
    for (int s = 0; s < 4; s++) {
        int r = srow + 8 * s;
        aofs[s] = (unsigned)((hb + r) * DFF) + (unsigned)(c8 * 8);
        bofs[s] = (unsigned)(r * DFF) + (unsigned)(c8 * 8);
    }
    int slot0 = (((l >> 4) ^ (lr & 7)) << 3);
    int slot1 = slot0 ^ 32;

    floatx4 acc[4][4];
    #pragma unroll
    for (int i = 0; i < 4; i++)
        #pragma unroll
        for (int j = 0; j < 4; j++) acc[i][j] = (floatx4){0.f, 0.f, 0.f, 0.f};

    #pragma unroll
    for (int s = 0; s < 4; s++) {
        gload16(hbuf + aofs[s], &smem[0][0][(w * 32 + 8 * s) * 64]);
        gload16(w2e  + bofs[s], &smem[0][1][(w * 32 + 8 * s) * 64]);
    }
    int buf = 0;
    for (int k0 = 0; k0 < DFF; k0 += BK) {
        __syncthreads();
        const unsigned short* A = smem[buf][0];
        const unsigned short* B = smem[buf][1];
        bf16x8 a0[4], b0[4], a1[4], b1f[4];
        #pragma unroll
        for (int i = 0; i < 4; i++) {
            a0[i]  = *(const bf16x8*)&A[(wm + 16 * i + lr) * 64 + slot0];
            a1[i]  = *(const bf16x8*)&A[(wm + 16 * i + lr) * 64 + slot1];
            b0[i]  = *(const bf16x8*)&B[(wn + 16 * i + lr) * 64 + slot0];
            b1f[i] = *(const bf16x8*)&B[(wn + 16 * i + lr) * 64 + slot1];
        }
        int nk = k0 + BK;
        if (nk < DFF) {
            int nbf = buf ^ 1;
            #pragma unroll
            for (int s = 0; s < 4; s++) {
                gload16(hbuf + aofs[s] + nk, &smem[nbf][0][(w * 32 + 8 * s) * 64]);
                gload16(w2e  + bofs[s] + nk, &smem[nbf][1][(w * 32 + 8 * s) * 64]);
            }
        }
        #pragma unroll
        for (int i = 0; i < 4; i++)
            #pragma unroll
            for (int j = 0; j < 4; j++)
                acc[i][j] = __builtin_amdgcn_mfma_f32_16x16x32_bf16(a0[i], b0[j], acc[i][j], 0, 0, 0);
        #pragma unroll
        for (int i = 0; i < 4; i++)
            #pragma unroll
            for (int j = 0; j < 4; j++)
                acc[i][j] = __builtin_amdgcn_mfma_f32_16x16x32_bf16(a1[i], b1f[j], acc[i][j], 0, 0, 0);
        buf ^= 1;
    }

    // epilogue: +b2, x gate weight, atomicAdd (2 adds/element total across experts)
    #pragma unroll
    for (int j = 0; j < 4; j++) {
        int n = nb * TN + wn + 16 * j + lr;
        float b2v = b2[e * HD + n];
        #pragma unroll
        for (int i = 0; i < 4; i++)
            #pragma unroll
            for (int rr = 0; rr < 4; rr++) {
                int m = wm + 16 * i + crow + rr;
                atomicAdd(&out[(size_t)tok_s[m] * HD + n], (acc[i][j][rr] + b2v) * wgt_s[m]);
            }
    }
}

// ---------------- fused fallback (ws too small): R2-style, swizzled ----------------
#define BMT 64
#define FK  64
#define XS_LD 520
#define HS_LD 72

__global__ __launch_bounds__(256, 2) void ffn_fused_fallback(
    const unsigned short* __restrict__ xb,
    const unsigned short* __restrict__ W1t, const float* __restrict__ b1,
    const unsigned short* __restrict__ W2t, const float* __restrict__ b2,
    const int* __restrict__ seg_count, const int* __restrict__ seg_token,
    const float* __restrict__ seg_w, float* __restrict__ out)
{
    int bid = blockIdx.x;
    int e = bid & 7;
    int g = bid >> 3;
    int cnt = seg_count[e];
    int n0 = g * BMT;
    if (n0 >= cnt) return;
    int rows = min(BMT, cnt - n0);

    __shared__ unsigned short xs[BMT * XS_LD];
    __shared__ unsigned short hs[BMT * HS_LD];
    __shared__ int   tok_s[BMT];
    __shared__ float wgt_s[BMT];

    int tid = threadIdx.x;
    if (tid < BMT) {
        int idx = (tid < rows) ? (n0 + tid) : n0;
        tok_s[tid] = seg_token[e * TOK + idx];
        wgt_s[tid] = (tid < rows) ? seg_w[e * TOK + idx] : 0.f;
    }
    __syncthreads();
    {
        int r = tid >> 2, q = tid & 3;
        const uint4* src = (const uint4*)(xb + (size_t)tok_s[r] * HD) + q * 16;
        uint4* dst = (uint4*)&xs[(size_t)r * XS_LD + q * 128];
        #pragma unroll
        for (int i = 0; i < 16; i++) dst[i] = src[i];
    }
    __syncthreads();

    int w = tid >> 6, l = tid & 63;
    int lr = l & 15, lk = (l >> 4) * 8, crow = (l >> 4) * 4;

    const unsigned short* w1e = W1t + (size_t)e * DFF * HD;
    const unsigned short* w2e = W2t + (size_t)e * HD * DFF;

    floatx4 acc2[4][8];
    #pragma unroll
    for (int i = 0; i < 4; i++)
        #pragma unroll
        for (int j = 0; j < 8; j++) acc2[i][j] = (floatx4){0.f, 0.f, 0.f, 0.f};

    for (int fc = 0; fc < DFF; fc += FK) {
        floatx4 acc1[4];
        #pragma unroll
        for (int t = 0; t < 4; t++) acc1[t] = (floatx4){0.f, 0.f, 0.f, 0.f};
        const unsigned short* w1c = w1e + (size_t)fc * HD;
        for (int ks = 0; ks < HD; ks += 32) {
            bf16x8 a = *(const bf16x8*)&xs[(16 * w + lr) * XS_LD + ks + lk];
            #pragma unroll
            for (int t = 0; t < 4; t++) {
                bf16x8 b = *(const bf16x8*)(w1c + (size_t)(16 * t + lr) * HD + ks + lk);
                acc1[t] = __builtin_amdgcn_mfma_f32_16x16x32_bf16(a, b, acc1[t], 0, 0, 0);
            }
        }
        __syncthreads();
        #pragma unroll
        for (int t = 0; t < 4; t++) {
            float b1v = b1[e * DFF + fc + 16 * t + lr];
            #pragma unroll
            for (int r = 0; r < 4; r++)
                hs[(16 * w + crow + r) * HS_LD + 16 * t + lr] = f2bf(gelu_exact(acc1[t][r] + b1v));
        }
        __syncthreads();
        #pragma unroll
        for (int ks = 0; ks < FK; ks += 32) {
            bf16x8 af[4];
            #pragma unroll
            for (int i = 0; i < 4; i++) af[i] = *(const bf16x8*)&hs[(16 * i + lr) * HS_LD + ks + lk];
            #pragma unroll 4
            for (int j = 0; j < 8; j++) {
                bf16x8 b = *(const bf16x8*)(w2e + (size_t)(128 * w + 16 * j + lr) * DFF + fc + ks + lk);
                #pragma unroll
                for (int i = 0; i < 4; i++)
                    acc2[i][j] = __builtin_amdgcn_mfma_f32_16x16x32_bf16(af[i], b, acc2[i][j], 0, 0, 0);
            }
        }
    }
    #pragma unroll
    for (int j = 0; j < 8; j++) {
        int n = 128 * w + 16 * j + lr;
        float b2v = b2[e * HD + n];
        #pragma unroll
        for (int i = 0; i < 4; i++)
            #pragma unroll
            for (int r = 0; r < 4; r++) {
                int m = 16 * i + crow + r;
                atomicAdd(&out[(size_t)tok_s[m] * HD + n], (acc2[i][j][r] + b2v) * wgt_s[m]);
            }
    }
}

// tiny finalize for fallback path
__global__ void finalize_kernel(const int* __restrict__ seg_count,
                                const float* __restrict__ probs_sum,
                                float* __restrict__ out_tail)
{
    int tid = threadIdx.x;
    if (tid < NE) out_tail[1 + tid] = (float)seg_count[tid];
    if (tid == 0) {
        float s = 0.f;
        #pragma unroll
        for (int e = 0; e < NE; e++) {
            float p = probs_sum[e] * (1.f / (float)TOK);
            s += p * p;
        }
        out_tail[0] = s * (float)NE;
    }
}

extern "C" void kernel_launch(void* const* d_in, const int* in_sizes, int n_in,
                              void* d_out, int out_size, void* d_ws, size_t ws_size,
                              hipStream_t stream)
{
    const float* x  = (const float*)d_in[0];
    const float* gW = (const float*)d_in[1];
    const float* gb = (const float*)d_in[2];
    const float* W1 = (const float*)d_in[3];
    const float* b1 = (const float*)d_in[4];
    const float* W2 = (const float*)d_in[5];
    const float* b2 = (const float*)d_in[6];
    float* out = (float*)d_out;

    // workspace layout (bytes)
    char* ws = (char*)d_ws;
    int*   seg_count = (int*)ws;                          // 32 B
    float* probs_sum = (float*)(ws + 32);                 // 32 B
    int*   seg_token = (int*)(ws + 262144);               // NE*TOK*4
    float* seg_w     = (float*)(ws + 262144 + (size_t)NE * TOK * 4);
    unsigned short* xb   = (unsigned short*)(ws + (1u  << 20));  //  8 MiB
    unsigned short* W1t  = (unsigned short*)(ws + (16u << 20));  // 16 MiB
    unsigned short* W2t  = (unsigned short*)(ws + (32u << 20));  // 16 MiB
    unsigned short* hbuf = (unsigned short*)(ws + (48u << 20));  // up to 71.3 MB

    const size_t WS_SPLIT = (size_t)(48u << 20) + (size_t)17408 * DFF * 2;  // ~122 MB

    hipMemsetAsync(d_ws, 0, 64, stream);
    hipMemsetAsync(d_out, 0, (size_t)TOK * HD * sizeof(float), stream);

    // gate (32 blocks) + weight transpose (4096 blocks), fused
    prep_kernel<<<4128, 256, 0, stream>>>(x, gW, gb, W1, W2,
                                          seg_count, probs_sum, seg_token, seg_w,
                                          xb, W1t, W2t);

    if (ws_size >= WS_SPLIT) {
        gemm1_kernel<<<NE * (DFF / TN) * 64, 256, 0, stream>>>(
            xb, W1t, b1, seg_count, probs_sum, seg_token, hbuf,
            out + (size_t)TOK * HD);
        gemm2_kernel<<<NE * (HD / TN) * 64, 256, 0, stream>>>(
            hbuf, W2t, b2, seg_count, seg_token, seg_w, out);
    } else {
        finalize_kernel<<<1, 64, 0, stream>>>(seg_count, probs_sum, out + (size_t)TOK * HD);
        ffn_fused_fallback<<<(TOK / BMT) * NE, 256, 0, stream>>>(
            xb, W1t, b1, W2t, b2, seg_count, seg_token, seg_w, out);
    }
}